// Round 3
// baseline (273.296 us; speedup 1.0000x reference)
//
#include <hip/hip_runtime.h>

#define LSEQ 512
#define NB 64
#define DELTA 16                       // barrier interval (steps); lag between bands = 64+DELTA
#define NSTEPS (LSEQ + 7 * (64 + DELTA) + 63)  // 1135

// Soft-DTW banded wavefront, one block per batch.
// 8 waves x 64 lanes; lane l of wave w owns DP row i = 64w + l + 1 and marches
// columns j = 1..512 with a per-lane skew of 1 (in-wave, via __shfl_up) and a
// per-wave lag of 64+DELTA columns (cross-wave, via LDS ring + barrier every
// DELTA steps). R[i][j] = d(i,j) + softmin_g(R[i-1][j-1], R[i-1][j], R[i][j-1]).
// Ring safety: wave w reads ring entry c at step c+lag_w-1; wave w-1 wrote it
// at step c+lag_w-17. Exactly one barrier (s % 16 == 0) lies between the write
// and the read in both waves' program order -> no race at any drift.
__global__ __launch_bounds__(512) void dtw_band(
    const float* __restrict__ pred, const float* __restrict__ target,
    float* __restrict__ part) {
  const int b = blockIdx.x;
  const int tid = threadIdx.x;
  const int w = tid >> 6;
  const int lane = tid & 63;
  const bool is_l0 = (lane == 0);
  const bool is_l63 = (lane == 63);

  __shared__ float tg[LSEQ];
  __shared__ float rings[7][128];  // rings[w]: bottom row of band w (row 64(w+1))

  const float p = pred[b * LSEQ + tid];  // pred[b][i-1], i = tid+1
  tg[tid] = target[b * LSEQ + tid];
  if (tid < 7) rings[tid][0] = INFINITY;  // column-0 boundary (never written in loop)
  __syncthreads();

  const int lag = w * (64 + DELTA);

  // softmin constants: exp((m-r)/g) = exp2((m-r)*C1); g*ln(s) = -C2N*log2(s)
  const float C1 = 14.4269504088896340736f;    // (1/g) * log2(e), g = 0.1
  const float C2N = -0.069314718055994530942f; // -g * ln(2)

  float vprev = INFINITY;  // own R[i][j-1]
  float r0 = INFINITY;     // R[i-1][j-1] (neighbor value from 2 steps ago)
  float r1pf = INFINITY;   // ring prefetch (lane 0, w>0)
  float tcur = tg[0];      // target prefetch (valid for the first active cell)

  for (int s = 1; s <= NSTEPS; ++s) {
    if ((s & (DELTA - 1)) == 0) __syncthreads();

    const int j = s - lag - lane;
    const bool active = (j >= 1) && (j <= LSEQ);

    // R[i-1][j]: previous-step value of lane-1 (wave-synchronous shuffle)
    float r1 = __shfl_up(vprev, 1);
    if (is_l0) r1 = (w == 0) ? INFINITY : r1pf;

    // prefetch next ring entry (column j+1) for lane 0 of waves 1..7
    if (is_l0 && w > 0) {
      const int jn = s + 1 - lag;
      r1pf = rings[w - 1][jn & 127];
    }

    float r0c = r0;
    // column-0 / corner boundary: R[i-1][0] = inf, except R[0][0] = 0.
    if (is_l0 && j == 1) r0c = (w == 0) ? 0.0f : INFINITY;

    const float diff = p - tcur;  // tcur = target[j-1], prefetched
    const float d = diff * diff;
    const float m = fminf(fminf(r0c, r1), vprev);  // finite for every real cell
    const float e = exp2f((m - r0c) * C1) + exp2f((m - r1) * C1) +
                    exp2f((m - vprev) * C1);       // in [1,3]
    const float v = (d + m) + C2N * log2f(e);

    if (active) {
      if (is_l63 && w < 7) rings[w][j & 127] = v;  // publish band-bottom row
      vprev = v;
    }
    r0 = r1;

    // prefetch target[(j+1)-1] for next step (index masked; garbage unused)
    tcur = tg[j & 511];
  }

  if (tid == LSEQ - 1) part[b] = vprev;  // R[512][512]
}

__global__ void dtw_reduce(const float* __restrict__ part,
                           float* __restrict__ out) {
  float v = part[threadIdx.x];
#pragma unroll
  for (int o = 32; o > 0; o >>= 1) v += __shfl_down(v, o);
  if (threadIdx.x == 0) out[0] = v * (1.0f / NB);
}

extern "C" void kernel_launch(void* const* d_in, const int* in_sizes, int n_in,
                              void* d_out, int out_size, void* d_ws,
                              size_t ws_size, hipStream_t stream) {
  const float* pred = (const float*)d_in[0];
  const float* target = (const float*)d_in[1];
  float* part = (float*)d_ws;

  dtw_band<<<NB, LSEQ, 0, stream>>>(pred, target, part);
  dtw_reduce<<<1, 64, 0, stream>>>(part, (float*)d_out);
}

// Round 4
// 202.901 us; speedup vs baseline: 1.3469x; 1.3469x over previous
//
#include <hip/hip_runtime.h>

#define LSEQ 512
#define NB 64
#define DELTA 16                       // barrier interval (steps); lag between bands = 64+DELTA
#define NSTEPS (LSEQ + 7 * (64 + DELTA) + 63)  // 1135

// Soft-DTW banded wavefront, one block per batch, 8 waves x 64 lanes.
// Lane l of wave w owns DP row i = 64w + l + 1. In-wave neighbor values move
// via DPP (VALU lane shift, no LDS latency); cross-wave via LDS ring + barrier
// every DELTA steps (ring write at step s-16 and read at step s always have
// exactly one barrier between them -> race-free for any drift <= DELTA).
__global__ __launch_bounds__(512) void dtw_band(
    const float* __restrict__ pred, const float* __restrict__ target,
    float* __restrict__ part) {
  const int b = blockIdx.x;
  const int tid = threadIdx.x;
  const int w = tid >> 6;
  const int lane = tid & 63;
  const bool is_l0 = (lane == 0);
  const bool fix16 = (lane != 0) && ((lane & 15) == 0);  // lanes 16,32,48
  const bool is_l63 = (lane == 63);
  const bool ring_rd = is_l0 && (w > 0);
  const bool ring_wr = is_l63 && (w < 7);

  __shared__ float tg[LSEQ];
  __shared__ float rings[7][128];  // rings[w]: bottom row of band w (row 64(w+1))

  const float p = pred[b * LSEQ + tid];  // pred[b][i-1], i = tid+1
  tg[tid] = target[b * LSEQ + tid];
  if (tid < 7) rings[tid][0] = INFINITY;  // column-0 boundary
  __syncthreads();

  const int lag = w * (64 + DELTA);
  const int INF_I = __float_as_int(INFINITY);

  // softmin: v = d + m + C2N * log2( sum exp2((m - r)*C1) ), args via fma.
  const float C1 = 14.4269504088896340736f;     // (1/g)*log2(e), g = 0.1
  const float C2N = -0.069314718055994530942f;  // -g*ln(2)

  float vprev = INFINITY;  // own R[i][j-1]
  float r0 = INFINITY;     // R[i-1][j-1] (previous step's r1)
  float r1pf = INFINITY;   // ring prefetch (lane 0 of waves 1..7)
  float tcur = tg[0];      // target[j-1] prefetch
  int j = 1 - lag - lane;  // column at step s=1

  for (int s = 1; s <= NSTEPS; ++s, ++j) {
    if ((s & (DELTA - 1)) == 0) __syncthreads();

    const bool active = ((unsigned)(j - 1)) < (unsigned)LSEQ;

    // R[i-1][j] = lane-1's vprev (pre-update), via DPP row_shr:1 + bcast15 fix.
    const int vi = __float_as_int(vprev);
    const float t1 = __int_as_float(
        __builtin_amdgcn_update_dpp(INF_I, vi, 0x111, 0xF, 0xF, false));
    const float t2 = __int_as_float(
        __builtin_amdgcn_update_dpp(INF_I, vi, 0x142, 0xF, 0xF, false));
    float r1 = fix16 ? t2 : t1;
    if (is_l0) r1 = (w == 0) ? INFINITY : r1pf;

    // prefetch next ring entry (column j+1) — consumed next step
    if (ring_rd) r1pf = rings[w - 1][(s + 1 - lag) & 127];

    float r0c = r0;
    // column-0 / corner boundary: R[i-1][0] = inf, except R[0][0] = 0.
    if (is_l0 && j == 1) r0c = (w == 0) ? 0.0f : INFINITY;

    const float diff = p - tcur;  // tcur = target[j-1], prefetched
    const float d = diff * diff;
    const float m = fminf(fminf(r0c, r1), vprev);  // finite for every real cell
    const float mC = m * C1;
    const float e = __builtin_amdgcn_exp2f(__builtin_fmaf(-r0c, C1, mC)) +
                    __builtin_amdgcn_exp2f(__builtin_fmaf(-r1, C1, mC)) +
                    __builtin_amdgcn_exp2f(__builtin_fmaf(-vprev, C1, mC));
    const float v = __builtin_fmaf(C2N, __builtin_amdgcn_logf(e), d + m);

    if (active) {
      if (ring_wr) rings[w][j & 127] = v;  // publish band-bottom row
      vprev = v;
    }
    r0 = r1;

    tcur = tg[j & 511];  // prefetch target[j] for next step (masked; OOB unused)
  }

  if (tid == LSEQ - 1) part[b] = vprev;  // R[512][512]
}

__global__ void dtw_reduce(const float* __restrict__ part,
                           float* __restrict__ out) {
  float v = part[threadIdx.x];
#pragma unroll
  for (int o = 32; o > 0; o >>= 1) v += __shfl_down(v, o);
  if (threadIdx.x == 0) out[0] = v * (1.0f / NB);
}

extern "C" void kernel_launch(void* const* d_in, const int* in_sizes, int n_in,
                              void* d_out, int out_size, void* d_ws,
                              size_t ws_size, hipStream_t stream) {
  const float* pred = (const float*)d_in[0];
  const float* target = (const float*)d_in[1];
  float* part = (float*)d_ws;

  dtw_band<<<NB, LSEQ, 0, stream>>>(pred, target, part);
  dtw_reduce<<<1, 64, 0, stream>>>(part, (float*)d_out);
}

// Round 5
// 132.231 us; speedup vs baseline: 2.0668x; 1.5345x over previous
//
#include <hip/hip_runtime.h>

#define LSEQ 512
#define NB 64
#define DELTA 16
#define NCHUNK 71  // 71*16 = 1136 steps >= 1135 needed

// Soft-DTW banded wavefront, one block per batch, 8 waves x 64 lanes.
// Lane l of wave w owns DP row i = 64w+l+1, marching columns j = s - 80w - l.
// All in-wave neighbor traffic via DPP wave_shr:1 (VALU pipe, no LDS latency).
// Cross-wave ring + target injection values are batch-read (uniform b128) at
// chunk top, right after the barrier, consumed via compile-time indices in the
// unrolled 16-step body -> no LDS read latency on the serial chain.
// Ring safety: entry e is written by wave w-1 at step e+80w-17; the largest
// entry chunk c reads is 16c-80w+16, written at step 16c-1 < chunk-c barrier.
__global__ __launch_bounds__(512) void dtw_band(
    const float* __restrict__ pred, const float* __restrict__ target,
    float* __restrict__ part) {
  const int b = blockIdx.x;
  const int tid = threadIdx.x;
  const int w = tid >> 6;
  const int lane = tid & 63;
  const bool is_l0 = (lane == 0);
  const bool is_wr = (lane == 63) && (w < 7);

  __shared__ float tg[LSEQ];
  __shared__ float rings[8][128];  // row w: bottom row of band w; row 7: INF dummy
  __shared__ float trash;

  const float p = pred[b * LSEQ + tid];  // pred[b][i-1]
  tg[tid] = target[b * LSEQ + tid];
  ((float*)rings)[tid] = INFINITY;        // init all 1024 ring slots
  ((float*)rings)[tid + 512] = INFINITY;  // (covers entry-0 boundary + dummy row)

  const int lag = w * (64 + DELTA);  // 80w, multiple of 16
  const float* __restrict__ ringP = rings[w == 0 ? 7 : w - 1];
  float* __restrict__ ringW = rings[w];

  const float C1 = 14.4269504088896340736f;     // (1/g)*log2(e), g = 0.1
  const float C2N = -0.069314718055994530942f;  // -g*ln(2)

  float vprev = INFINITY;                   // own R[i][j-1]
  float r0 = (tid == 0) ? 0.0f : INFINITY;  // R[i-1][j-1]; seed = R[0][0]
  float tcur = 0.0f;                        // target[j-1] (flows down lanes)

  for (int c = 0; c < NCHUNK; ++c) {
    __syncthreads();
    const int base = 16 * c - lag;  // multiple of 16 (may be negative)
    // chunk-batched uniform loads (broadcast reads, 16B-aligned)
    const float4* tp = (const float4*)&tg[base & 511];
    const float4 tq0 = tp[0], tq1 = tp[1], tq2 = tp[2], tq3 = tp[3];
    const float4* rp = (const float4*)&ringP[base & 127];
    const float4 rq0 = rp[0], rq1 = rp[1], rq2 = rp[2], rq3 = rp[3];
    const float r16 = ringP[(base + 16) & 127];
    const float tt[16] = {tq0.x, tq0.y, tq0.z, tq0.w, tq1.x, tq1.y, tq1.z,
                          tq1.w, tq2.x, tq2.y, tq2.z, tq2.w, tq3.x, tq3.y,
                          tq3.z, tq3.w};
    const float rr[17] = {rq0.x, rq0.y, rq0.z, rq0.w, rq1.x, rq1.y,
                          rq1.z, rq1.w, rq2.x, rq2.y, rq2.z, rq2.w,
                          rq3.x, rq3.y, rq3.z, rq3.w, r16};

    int j = 16 * c + 1 - lag - lane;
#pragma unroll
    for (int u = 0; u < 16; ++u, ++j) {
      // full-wave lane shift (DPP wave_shr:1); lane 0 injects fresh values
      const float tsh = __int_as_float(__builtin_amdgcn_update_dpp(
          0, __float_as_int(tcur), 0x138, 0xF, 0xF, false));
      tcur = is_l0 ? tt[u] : tsh;  // target[j-1]
      const float vsh = __int_as_float(__builtin_amdgcn_update_dpp(
          0, __float_as_int(vprev), 0x138, 0xF, 0xF, false));
      const float r1 = is_l0 ? rr[u + 1] : vsh;  // R[i-1][j]

      const float diff = p - tcur;
      const float d = diff * diff;
      const float m = fminf(fminf(r0, r1), vprev);  // finite for every real cell
      const float mC = m * C1;
      const float e = __builtin_amdgcn_exp2f(__builtin_fmaf(-r0, C1, mC)) +
                      __builtin_amdgcn_exp2f(__builtin_fmaf(-r1, C1, mC)) +
                      __builtin_amdgcn_exp2f(__builtin_fmaf(-vprev, C1, mC));
      const float v = __builtin_fmaf(C2N, __builtin_amdgcn_logf(e), d + m);

      const bool active = ((unsigned)(j - 1)) < (unsigned)LSEQ;
      float* wp = (is_wr && active) ? &ringW[j & 127] : &trash;  // branchless
      *wp = v;
      vprev = active ? v : vprev;
      r0 = r1;
    }
  }

  if (tid == 511) part[b] = vprev;  // R[512][512]
}

__global__ void dtw_reduce(const float* __restrict__ part,
                           float* __restrict__ out) {
  float v = part[threadIdx.x];
#pragma unroll
  for (int o = 32; o > 0; o >>= 1) v += __shfl_down(v, o);
  if (threadIdx.x == 0) out[0] = v * (1.0f / NB);
}

extern "C" void kernel_launch(void* const* d_in, const int* in_sizes, int n_in,
                              void* d_out, int out_size, void* d_ws,
                              size_t ws_size, hipStream_t stream) {
  const float* pred = (const float*)d_in[0];
  const float* target = (const float*)d_in[1];
  float* part = (float*)d_ws;

  dtw_band<<<NB, LSEQ, 0, stream>>>(pred, target, part);
  dtw_reduce<<<1, 64, 0, stream>>>(part, (float*)d_out);
}

// Round 7
// 114.281 us; speedup vs baseline: 2.3914x; 1.1571x over previous
//
#include <hip/hip_runtime.h>

#define LSEQ 512
#define NB 64
#define NCHUNK 78  // 16*78 = 1248 >= 512 + 7*96 + 63 = 1247 steps

// lane l-1's value -> lane l (DPP wave_shr:1, pure VALU). Lane 0 keeps old;
// every use overwrites lane 0 via select.
__device__ __forceinline__ float dpp_shr1(float x) {
  return __int_as_float(
      __builtin_amdgcn_update_dpp(0, __float_as_int(x), 0x138, 0xF, 0xF, false));
}

// Batched uniform LDS loads for one 16-step chunk (broadcast b128 reads).
__device__ __forceinline__ void load_chunk(int cbase, const float* tgp,
                                           const float* ringP, float (&tt)[16],
                                           float (&rr)[17]) {
  const float4* tp = (const float4*)&tgp[cbase & 511];  // cbase mult of 16
  const float4 t0 = tp[0], t1 = tp[1], t2 = tp[2], t3 = tp[3];
  tt[0] = t0.x; tt[1] = t0.y; tt[2] = t0.z; tt[3] = t0.w;
  tt[4] = t1.x; tt[5] = t1.y; tt[6] = t1.z; tt[7] = t1.w;
  tt[8] = t2.x; tt[9] = t2.y; tt[10] = t2.z; tt[11] = t2.w;
  tt[12] = t3.x; tt[13] = t3.y; tt[14] = t3.z; tt[15] = t3.w;
  const float4* rp = (const float4*)&ringP[cbase & 127];
  const float4 q0 = rp[0], q1 = rp[1], q2 = rp[2], q3 = rp[3];
  rr[0] = q0.x; rr[1] = q0.y; rr[2] = q0.z; rr[3] = q0.w;
  rr[4] = q1.x; rr[5] = q1.y; rr[6] = q1.z; rr[7] = q1.w;
  rr[8] = q2.x; rr[9] = q2.y; rr[10] = q2.z; rr[11] = q2.w;
  rr[12] = q3.x; rr[13] = q3.y; rr[14] = q3.z; rr[15] = q3.w;
  rr[16] = ringP[(cbase + 16) & 127];
}

// 16 DP steps. Scaled domain: R' = R*C1, inputs pre-scaled by sqrt(C1);
// v' = d' + m' - log2e * log2(sum exp2(m'-r')).
template <bool FULL>
__device__ __forceinline__ void chunk_body(int cbase, const float (&tt)[16],
                                           const float (&rr)[17], float p,
                                           bool is_l0, bool is_wr, int lane,
                                           float& vprev, float& r0, float& tcur,
                                           float* __restrict__ ringW,
                                           float* sink) {
#pragma unroll
  for (int u = 0; u < 16; ++u) {
    const float tsh = dpp_shr1(tcur);
    tcur = is_l0 ? tt[u] : tsh;  // target'[j-1]
    const float vsh = dpp_shr1(vprev);
    const float r1 = is_l0 ? rr[u + 1] : vsh;  // R'[i-1][j]

    const float diff = p - tcur;
    const float d = diff * diff;
    const float m = fminf(fminf(r0, r1), vprev);
    const float e = __builtin_amdgcn_exp2f(m - r0) +
                    __builtin_amdgcn_exp2f(m - r1) +
                    __builtin_amdgcn_exp2f(m - vprev);  // in [1,3]
    const float v =
        __builtin_fmaf(-1.44269504f, __builtin_amdgcn_logf(e), d + m);

    // Ring slot = lane 63's column j = cbase + 1 + u - 63 (R6 bug: used lane
    // 0's column, shifting all published rows by 63 -> INF/NaN downstream).
    const int slot = (cbase + u - 62) & 127;
    if (FULL) {
      float* wp = is_wr ? &ringW[slot] : sink;  // per-lane sink: no conflicts
      *wp = v;
      vprev = v;
    } else {
      const int j = cbase + 1 + u - lane;
      const bool active = ((unsigned)(j - 1)) < (unsigned)LSEQ;
      float* wp = (is_wr && active) ? &ringW[slot] : sink;
      *wp = v;
      vprev = active ? v : vprev;
    }
    r0 = r1;
  }
}

// Soft-DTW banded wavefront, one block per batch, 8 waves x 64 lanes.
// Lane l of wave w owns row i = 64w+l+1, column j = s - 96w - l at step s.
// In-wave neighbors via DPP; cross-wave via LDS ring. Ring entries for chunk X
// (prefetched right after the barrier at top of chunk X-1) are written by wave
// w-1 no later than step 16X-17 (inside its chunk X-2), so the top-of-(X-1)
// barrier always separates write from read; writer-ahead writes are 18..49
// columns beyond the read window (disjoint, < 128 so no slot aliasing).
__global__ __launch_bounds__(512) void dtw_band(
    const float* __restrict__ pred, const float* __restrict__ target,
    float* __restrict__ part) {
  const int b = blockIdx.x;
  const int tid = threadIdx.x;
  const int w = tid >> 6;
  const int lane = tid & 63;
  const bool is_l0 = (lane == 0);
  const bool is_wr = (lane == 63) && (w < 7);

  __shared__ float tg[LSEQ];
  __shared__ float rings[8][128];  // row w: bottom row of band w; row 7: INF
  __shared__ float trash[64];

  const float SC = 3.79828146f;  // sqrt(C1), C1 = (1/g)*log2(e), g = 0.1
  const float p = pred[b * LSEQ + tid] * SC;
  tg[tid] = target[b * LSEQ + tid] * SC;
  ((float*)rings)[tid] = INFINITY;
  ((float*)rings)[tid + 512] = INFINITY;
  __syncthreads();

  const int lag = w * 96;
  const int cw0 = 6 * w;  // wave-active chunks: [cw0, cw0+35]
  const float* __restrict__ ringP = rings[w == 0 ? 7 : w - 1];
  float* __restrict__ ringW = rings[w];
  float* sink = &trash[lane];

  float vprev = INFINITY;                   // R'[i][j-1]
  float r0 = (tid == 0) ? 0.0f : INFINITY;  // R'[i-1][j-1]; seed R'[0][0]=0
  float tcur = 0.0f;                        // target'[j-1] (flows down lanes)

  float ttA[16], rrA[17], ttB[16], rrB[17];
  load_chunk(-lag, tg, ringP, ttA, rrA);  // chunk 0 (used only by wave 0)

  for (int c = 0; c < NCHUNK; c += 2) {
    __syncthreads();  // top of chunk c
    if (c + 1 >= cw0 && c + 1 <= cw0 + 35)
      load_chunk(16 * (c + 1) - lag, tg, ringP, ttB, rrB);
    if (c >= cw0 && c <= cw0 + 35) {
      if (c >= cw0 + 4 && c <= cw0 + 31)
        chunk_body<true>(16 * c - lag, ttA, rrA, p, is_l0, is_wr, lane, vprev,
                         r0, tcur, ringW, sink);
      else
        chunk_body<false>(16 * c - lag, ttA, rrA, p, is_l0, is_wr, lane, vprev,
                          r0, tcur, ringW, sink);
    }

    __syncthreads();  // top of chunk c+1
    if (c + 2 >= cw0 && c + 2 <= cw0 + 35)
      load_chunk(16 * (c + 2) - lag, tg, ringP, ttA, rrA);
    if (c + 1 >= cw0 && c + 1 <= cw0 + 35) {
      if (c + 1 >= cw0 + 4 && c + 1 <= cw0 + 31)
        chunk_body<true>(16 * (c + 1) - lag, ttB, rrB, p, is_l0, is_wr, lane,
                         vprev, r0, tcur, ringW, sink);
      else
        chunk_body<false>(16 * (c + 1) - lag, ttB, rrB, p, is_l0, is_wr, lane,
                          vprev, r0, tcur, ringW, sink);
    }
  }

  if (tid == LSEQ - 1) part[b] = vprev * 0.069314718f;  // unscale: * 1/C1
}

__global__ void dtw_reduce(const float* __restrict__ part,
                           float* __restrict__ out) {
  float v = part[threadIdx.x];
#pragma unroll
  for (int o = 32; o > 0; o >>= 1) v += __shfl_down(v, o);
  if (threadIdx.x == 0) out[0] = v * (1.0f / NB);
}

extern "C" void kernel_launch(void* const* d_in, const int* in_sizes, int n_in,
                              void* d_out, int out_size, void* d_ws,
                              size_t ws_size, hipStream_t stream) {
  const float* pred = (const float*)d_in[0];
  const float* target = (const float*)d_in[1];
  float* part = (float*)d_ws;

  dtw_band<<<NB, LSEQ, 0, stream>>>(pred, target, part);
  dtw_reduce<<<1, 64, 0, stream>>>(part, (float*)d_out);
}

// Round 8
// 113.145 us; speedup vs baseline: 2.4154x; 1.0100x over previous
//
#include <hip/hip_runtime.h>

#define LSEQ 512
#define NB 64
#define NCHUNK 78  // 16*78 = 1248 >= 512 + 7*96 + 63 = 1247 steps

// lane l-1's value -> lane l (DPP wave_shr:1, pure VALU). Lane 0 keeps old;
// every use overwrites lane 0 via select.
__device__ __forceinline__ float dpp_shr1(float x) {
  return __int_as_float(
      __builtin_amdgcn_update_dpp(0, __float_as_int(x), 0x138, 0xF, 0xF, false));
}

// Batched uniform LDS loads for one 16-step chunk (broadcast b128 reads).
__device__ __forceinline__ void load_chunk(int cbase, const float* tgp,
                                           const float* ringP, float (&tt)[16],
                                           float (&rr)[17]) {
  const float4* tp = (const float4*)&tgp[cbase & 511];  // cbase mult of 16
  const float4 t0 = tp[0], t1 = tp[1], t2 = tp[2], t3 = tp[3];
  tt[0] = t0.x; tt[1] = t0.y; tt[2] = t0.z; tt[3] = t0.w;
  tt[4] = t1.x; tt[5] = t1.y; tt[6] = t1.z; tt[7] = t1.w;
  tt[8] = t2.x; tt[9] = t2.y; tt[10] = t2.z; tt[11] = t2.w;
  tt[12] = t3.x; tt[13] = t3.y; tt[14] = t3.z; tt[15] = t3.w;
  const float4* rp = (const float4*)&ringP[cbase & 127];
  const float4 q0 = rp[0], q1 = rp[1], q2 = rp[2], q3 = rp[3];
  rr[0] = q0.x; rr[1] = q0.y; rr[2] = q0.z; rr[3] = q0.w;
  rr[4] = q1.x; rr[5] = q1.y; rr[6] = q1.z; rr[7] = q1.w;
  rr[8] = q2.x; rr[9] = q2.y; rr[10] = q2.z; rr[11] = q2.w;
  rr[12] = q3.x; rr[13] = q3.y; rr[14] = q3.z; rr[15] = q3.w;
  rr[16] = ringP[(cbase + 16) & 127];
}

// Pin chunk values into VGPRs at this program point. Without this, the
// compiler sinks the LDS loads to their uses (saving 66 regs, VGPR=52 in R7),
// putting a ~150cy lgkmcnt wait on EVERY step's critical path.
__device__ __forceinline__ void force_regs(float (&tt)[16], float (&rr)[17]) {
#pragma unroll
  for (int i = 0; i < 16; ++i) asm volatile("" : "+v"(tt[i]));
#pragma unroll
  for (int i = 0; i < 17; ++i) asm volatile("" : "+v"(rr[i]));
}

// 16 DP steps. Scaled domain: R' = R*C1 (C1 = (1/g)*log2e), inputs pre-scaled
// by sqrt(C1). Identity: v' = d' + m' - log2( sum exp2(m'-r') ).
// (R7 bug: multiplied the log2 term by log2e -> ~3.0 accumulated bias.)
template <bool FULL>
__device__ __forceinline__ void chunk_body(int cbase, const float (&tt)[16],
                                           const float (&rr)[17], float p,
                                           bool is_l0, bool is_wr, int lane,
                                           float& vprev, float& r0, float& tcur,
                                           float* __restrict__ ringW,
                                           float* sink) {
#pragma unroll
  for (int u = 0; u < 16; ++u) {
    const float tsh = dpp_shr1(tcur);
    tcur = is_l0 ? tt[u] : tsh;  // target'[j-1]
    const float vsh = dpp_shr1(vprev);
    const float r1 = is_l0 ? rr[u + 1] : vsh;  // R'[i-1][j]

    const float diff = p - tcur;
    const float d = diff * diff;
    const float m = fminf(fminf(r0, r1), vprev);
    const float e = __builtin_amdgcn_exp2f(m - r0) +
                    __builtin_amdgcn_exp2f(m - r1) +
                    __builtin_amdgcn_exp2f(m - vprev);  // in [1,3]
    const float v = (d + m) - __builtin_amdgcn_logf(e);

    const int slot = (cbase + u - 62) & 127;  // lane 63's column j & 127
    if (FULL) {
      float* wp = is_wr ? &ringW[slot] : sink;  // per-lane sink: no conflicts
      *wp = v;
      vprev = v;
    } else {
      const int j = cbase + 1 + u - lane;
      const bool active = ((unsigned)(j - 1)) < (unsigned)LSEQ;
      float* wp = (is_wr && active) ? &ringW[slot] : sink;
      *wp = v;
      vprev = active ? v : vprev;
    }
    r0 = r1;
  }
}

// Soft-DTW banded wavefront, one block per batch, 8 waves x 64 lanes.
// Lane l of wave w owns row i = 64w+l+1, column j = s - 96w - l at step s.
// In-wave neighbors via DPP; cross-wave via LDS ring. Ring entries for chunk X
// are written by wave w-1 no later than step 16X-17 (its chunk X-2); loads for
// chunk X issue after the top-of-(X-1) barrier -> race-free. Concurrent
// writer-ahead columns are 50..65 past the read window (disjoint, < 128).
__global__ __launch_bounds__(512) void dtw_band(
    const float* __restrict__ pred, const float* __restrict__ target,
    float* __restrict__ part) {
  const int b = blockIdx.x;
  const int tid = threadIdx.x;
  const int w = tid >> 6;
  const int lane = tid & 63;
  const bool is_l0 = (lane == 0);
  const bool is_wr = (lane == 63) && (w < 7);

  __shared__ float tg[LSEQ];
  __shared__ float rings[8][128];  // row w: bottom row of band w; row 7: INF
  __shared__ float trash[64];

  const float SC = 3.79828146f;  // sqrt(C1), C1 = (1/g)*log2(e), g = 0.1
  const float p = pred[b * LSEQ + tid] * SC;
  tg[tid] = target[b * LSEQ + tid] * SC;
  ((float*)rings)[tid] = INFINITY;
  ((float*)rings)[tid + 512] = INFINITY;
  __syncthreads();

  const int lag = w * 96;
  const int cw0 = 6 * w;  // wave-active chunks: [cw0, cw0+35]
  const float* __restrict__ ringP = rings[w == 0 ? 7 : w - 1];
  float* __restrict__ ringW = rings[w];
  float* sink = &trash[lane];

  float vprev = INFINITY;                   // R'[i][j-1]
  float r0 = (tid == 0) ? 0.0f : INFINITY;  // R'[i-1][j-1]; seed R'[0][0]=0
  float tcur = 0.0f;                        // target'[j-1] (flows down lanes)

  float ttA[16], rrA[17], ttB[16], rrB[17];
  load_chunk(-lag, tg, ringP, ttA, rrA);  // chunk 0 (used only by wave 0)

  for (int c = 0; c < NCHUNK; c += 2) {
    __syncthreads();  // top of chunk c
    if (c + 1 >= cw0 && c + 1 <= cw0 + 35)
      load_chunk(16 * (c + 1) - lag, tg, ringP, ttB, rrB);
    if (c >= cw0 && c <= cw0 + 35) {
      force_regs(ttA, rrA);  // loads issued >=1 full chunk-body earlier
      if (c >= cw0 + 4 && c <= cw0 + 31)
        chunk_body<true>(16 * c - lag, ttA, rrA, p, is_l0, is_wr, lane, vprev,
                         r0, tcur, ringW, sink);
      else
        chunk_body<false>(16 * c - lag, ttA, rrA, p, is_l0, is_wr, lane, vprev,
                          r0, tcur, ringW, sink);
    }

    __syncthreads();  // top of chunk c+1
    if (c + 2 >= cw0 && c + 2 <= cw0 + 35)
      load_chunk(16 * (c + 2) - lag, tg, ringP, ttA, rrA);
    if (c + 1 >= cw0 && c + 1 <= cw0 + 35) {
      force_regs(ttB, rrB);
      if (c + 1 >= cw0 + 4 && c + 1 <= cw0 + 31)
        chunk_body<true>(16 * (c + 1) - lag, ttB, rrB, p, is_l0, is_wr, lane,
                         vprev, r0, tcur, ringW, sink);
      else
        chunk_body<false>(16 * (c + 1) - lag, ttB, rrB, p, is_l0, is_wr, lane,
                          vprev, r0, tcur, ringW, sink);
    }
  }

  if (tid == LSEQ - 1) part[b] = vprev * 0.069314718f;  // unscale: * 1/C1
}

__global__ void dtw_reduce(const float* __restrict__ part,
                           float* __restrict__ out) {
  float v = part[threadIdx.x];
#pragma unroll
  for (int o = 32; o > 0; o >>= 1) v += __shfl_down(v, o);
  if (threadIdx.x == 0) out[0] = v * (1.0f / NB);
}

extern "C" void kernel_launch(void* const* d_in, const int* in_sizes, int n_in,
                              void* d_out, int out_size, void* d_ws,
                              size_t ws_size, hipStream_t stream) {
  const float* pred = (const float*)d_in[0];
  const float* target = (const float*)d_in[1];
  float* part = (float*)d_ws;

  dtw_band<<<NB, LSEQ, 0, stream>>>(pred, target, part);
  dtw_reduce<<<1, 64, 0, stream>>>(part, (float*)d_out);
}

// Round 9
// 98.298 us; speedup vs baseline: 2.7803x; 1.1510x over previous
//
#include <hip/hip_runtime.h>

#define LSEQ 512
#define NB 64
#define NCHUNK 71  // 71*16 = 1136 >= 512 + 7*80 + 63 = 1135 steps

// lane l-1's value -> lane l (DPP wave_shr:1, pure VALU).
__device__ __forceinline__ float dpp_shr1(float x) {
  return __int_as_float(
      __builtin_amdgcn_update_dpp(0, __float_as_int(x), 0x138, 0xF, 0xF, false));
}

// One DP cell in the scaled domain (R' = R*C1, inputs pre-scaled by sqrt(C1)):
// v' = (d' + m') - log2( 1 + exp2(m'-med) + exp2(m'-max) ), m' = min3.
// The min's exp2 term is exp2(0)=1 (ties: med==min also gives 1) -> 3 trans
// ops instead of 4. INF preds give exp2(-INF)=0; all-INF gives NaN, which only
// occurs for inactive cells (vprev guarded there).
__device__ __forceinline__ float cell(float p, float tcur, float r0, float r1,
                                      float vprev) {
  const float diff = p - tcur;
  const float m = fminf(fminf(r0, r1), vprev);        // v_min3
  const float dm = __builtin_fmaf(diff, diff, m);     // d' + m'
  const float md = __builtin_amdgcn_fmed3f(r0, r1, vprev);
  const float mx = fmaxf(fmaxf(r0, r1), vprev);       // v_max3
  const float e = 1.0f + (__builtin_amdgcn_exp2f(m - md) +
                          __builtin_amdgcn_exp2f(m - mx));  // in [1,3]
  return dm - __builtin_amdgcn_logf(e);               // v_log_f32 = log2
}

// 4 DP steps (sub-group g: u = U0..U0+3). tq = tg'[cbase+U0 .. +3] (lane-0
// target injection), rq = ring slots cbase+U0..+3, rnx = slot cbase+U0+4.
// r1 for step u uses ring slot cbase+u+1.
template <bool FULL, int U0>
__device__ __forceinline__ void four_steps(int cbase, float4 tq, float4 rq,
                                           float rnx, float p, bool is_l0,
                                           int lane, float& vprev, float& r0,
                                           float& tcur, float (&vv)[16]) {
#pragma unroll
  for (int k = 0; k < 4; ++k) {
    const float ttk = (k == 0) ? tq.x : (k == 1) ? tq.y : (k == 2) ? tq.z : tq.w;
    const float rrk = (k == 0) ? rq.y : (k == 1) ? rq.z : (k == 2) ? rq.w : rnx;
    const float tsh = dpp_shr1(tcur);
    tcur = is_l0 ? ttk : tsh;  // target'[j-1]
    const float vsh = dpp_shr1(vprev);
    const float r1 = is_l0 ? rrk : vsh;  // R'[i-1][j]
    const float v = cell(p, tcur, r0, r1, vprev);
    vv[U0 + k] = v;
    if (FULL) {
      vprev = v;
    } else {
      const int j = cbase + 1 + U0 + k - lane;
      vprev = (((unsigned)(j - 1)) < (unsigned)LSEQ) ? v : vprev;
    }
    r0 = r1;
  }
}

// One 16-step chunk: sub-group-pipelined uniform LDS loads (each sub-body's
// data issued >= 1 sub-body (~400cy) before first use; live range = 8 floats,
// so no register-pressure sinking), then lane 63 bursts its 16 row-bottom
// values into the ring as 8x ds_write_b64 (slot base = cbase-62 = 2 mod 4 ->
// byte addr = 8 mod 16, 8B-aligned).
template <bool FULL>
__device__ __forceinline__ void chunk16(int cbase, const float* tgp,
                                        const float* ringP, float* ringW,
                                        float p, bool is_l0, bool is_wr,
                                        int lane, float& vprev, float& r0,
                                        float& tcur) {
  const float4* t4 = (const float4*)tgp;
  const float4* r4 = (const float4*)ringP;
  float vv[16];
  float4 t0 = t4[((cbase + 0) & 511) >> 2], q0 = r4[((cbase + 0) & 127) >> 2];
  float4 t1 = t4[((cbase + 4) & 511) >> 2], q1 = r4[((cbase + 4) & 127) >> 2];
  four_steps<FULL, 0>(cbase, t0, q0, q1.x, p, is_l0, lane, vprev, r0, tcur, vv);
  float4 t2 = t4[((cbase + 8) & 511) >> 2], q2 = r4[((cbase + 8) & 127) >> 2];
  four_steps<FULL, 4>(cbase, t1, q1, q2.x, p, is_l0, lane, vprev, r0, tcur, vv);
  float4 t3 = t4[((cbase + 12) & 511) >> 2], q3 = r4[((cbase + 12) & 127) >> 2];
  const float rEnd = ringP[(cbase + 16) & 127];
  four_steps<FULL, 8>(cbase, t2, q2, q3.x, p, is_l0, lane, vprev, r0, tcur, vv);
  four_steps<FULL, 12>(cbase, t3, q3, rEnd, p, is_l0, lane, vprev, r0, tcur, vv);

  if (is_wr) {
    const int wb = (cbase - 62) & 127;  // lane 63's first column this chunk
#pragma unroll
    for (int k = 0; k < 8; ++k) {
      *(float2*)&ringW[(wb + 2 * k) & 127] =
          make_float2(vv[2 * k], vv[2 * k + 1]);
    }
  }
}

// Soft-DTW banded wavefront, one block per batch, 8 waves x 64 lanes.
// Lane l of wave w owns row i = 64w+l+1, column j = s - 80w - l at step s.
// In-wave neighbors via DPP; cross-wave via LDS ring + barrier every 16 steps.
// Ring entry j (needed by wave w's chunk c, read after barrier top-of-c) is
// written by wave w-1 during its chunk <= c-1 (step j+80w-17 <= 16c-1), burst
// before barrier top-of-c -> race-free. Concurrent same-window writes land in
// slots cbase+18..+33, disjoint from reads cbase..+16 (mod-128 gap < 128).
__global__ __launch_bounds__(512) void dtw_band(
    const float* __restrict__ pred, const float* __restrict__ target,
    float* __restrict__ part) {
  const int b = blockIdx.x;
  const int tid = threadIdx.x;
  const int w = tid >> 6;
  const int lane = tid & 63;
  const bool is_l0 = (lane == 0);
  const bool is_wr = (lane == 63) && (w < 7);

  __shared__ float tg[LSEQ];
  __shared__ float rings[8][128];  // row w: bottom row of band w; row 7: INF

  const float SC = 3.79828146f;  // sqrt(C1), C1 = (1/g)*log2(e), g = 0.1
  const float p = pred[b * LSEQ + tid] * SC;
  tg[tid] = target[b * LSEQ + tid] * SC;
  ((float*)rings)[tid] = INFINITY;
  ((float*)rings)[tid + 512] = INFINITY;

  const int lag = w * 80;
  const int cw0 = 5 * w;  // wave-active chunks: [cw0, cw0+35]
  const float* __restrict__ ringP = rings[w == 0 ? 7 : w - 1];
  float* __restrict__ ringW = rings[w];

  float vprev = INFINITY;                   // R'[i][j-1]
  float r0 = (tid == 0) ? 0.0f : INFINITY;  // R'[i-1][j-1]; seed R'[0][0]=0
  float tcur = 0.0f;                        // target'[j-1] (flows down lanes)

  for (int c = 0; c < NCHUNK; ++c) {
    __syncthreads();  // top of chunk c (also covers the init writes at c=0)
    if (c < cw0 || c > cw0 + 35) continue;  // wave-uniform
    const int cbase = 16 * c - lag;         // >= 0 for active chunks
    if (c >= cw0 + 4 && c <= cw0 + 31)
      chunk16<true>(cbase, tg, ringP, ringW, p, is_l0, is_wr, lane, vprev, r0,
                    tcur);
    else
      chunk16<false>(cbase, tg, ringP, ringW, p, is_l0, is_wr, lane, vprev, r0,
                     tcur);
  }

  if (tid == LSEQ - 1) part[b] = vprev * 0.069314718f;  // unscale: * 1/C1
}

__global__ void dtw_reduce(const float* __restrict__ part,
                           float* __restrict__ out) {
  float v = part[threadIdx.x];
#pragma unroll
  for (int o = 32; o > 0; o >>= 1) v += __shfl_down(v, o);
  if (threadIdx.x == 0) out[0] = v * (1.0f / NB);
}

extern "C" void kernel_launch(void* const* d_in, const int* in_sizes, int n_in,
                              void* d_out, int out_size, void* d_ws,
                              size_t ws_size, hipStream_t stream) {
  const float* pred = (const float*)d_in[0];
  const float* target = (const float*)d_in[1];
  float* part = (float*)d_ws;

  dtw_band<<<NB, LSEQ, 0, stream>>>(pred, target, part);
  dtw_reduce<<<1, 64, 0, stream>>>(part, (float*)d_out);
}